// Round 14
// baseline (334.779 us; speedup 1.0000x reference)
//
#include <hip/hip_runtime.h>
#include <math.h>

// ---------------------------------------------------------------------------
// DifferentiablePooling: 2-layer GCN + softmax + spatial loss
// Round 14: revert fused kernel to 4-wave (round-12 best); csr interleaved
//           int2 {src,nrm}; agg2 8-deep + stride-64 g; loss packed-f16 dot.
// ---------------------------------------------------------------------------

typedef __attribute__((ext_vector_type(8))) short bf16x8;
typedef __attribute__((ext_vector_type(4))) float f32x4;
typedef __attribute__((ext_vector_type(4))) unsigned int u32x4;
typedef _Float16 f16;
typedef __attribute__((ext_vector_type(2))) _Float16 f16x2;
typedef __attribute__((ext_vector_type(4))) _Float16 f16x4;
typedef __attribute__((ext_vector_type(8))) _Float16 f16x8;

__device__ inline unsigned short f32_to_bf16(float f) {
    unsigned u = __float_as_uint(f);
    unsigned r = u + 0x7FFFu + ((u >> 16) & 1u);   // RTNE; inputs are finite
    return (unsigned short)(r >> 16);
}
__device__ inline float bf16_to_f32(unsigned short h) {
    return __uint_as_float((unsigned)h << 16);
}

// async global->LDS, 16B per lane; lptr must be wave-uniform (HW adds lane*16)
__device__ inline void glds16(const void* g, void* l) {
    __builtin_amdgcn_global_load_lds(
        (const __attribute__((address_space(1))) unsigned int*)g,
        (__attribute__((address_space(3))) unsigned int*)l, 16, 0, 0);
}

// ---- edge dtype detection (int64 vs int32 on device) ----------------------
__global__ void detect_i64_kernel(const unsigned* __restrict__ w, int* __restrict__ flag) {
    __shared__ int red[256];
    int cnt = 0;
    for (int i = threadIdx.x; i < 4096; i += 256)
        cnt += (w[2 * i + 1] == 0u) ? 1 : 0;   // high words of int64 are 0
    red[threadIdx.x] = cnt;
    __syncthreads();
    for (int s = 128; s > 0; s >>= 1) {
        if ((int)threadIdx.x < s) red[threadIdx.x] += red[threadIdx.x + s];
        __syncthreads();
    }
    if (threadIdx.x == 0) *flag = (red[0] > 2048) ? 1 : 0;
}

// convert + fused degree count (atomicAdd on dst)
__global__ void convert_edges_kernel(const void* __restrict__ ei, int* __restrict__ es,
                                     int* __restrict__ ed, int* __restrict__ cnt,
                                     int E, const int* __restrict__ flag) {
    int idx = blockIdx.x * blockDim.x + threadIdx.x;
    if (idx >= 2 * E) return;
    int v;
    if (*flag) v = (int)((const long long*)ei)[idx];
    else       v = ((const int*)ei)[idx];
    if (idx < E) es[idx] = v;
    else { ed[idx - E] = v; atomicAdd(&cnt[v], 1); }
}

// hierarchical scan: (1) per-block inclusive scan -> row_ptr[i+1], block totals
__global__ __launch_bounds__(1024) void scan_block_kernel(const int* __restrict__ cnt,
        int* __restrict__ row_ptr, int* __restrict__ btot, int n) {
    __shared__ int buf[1024];
    int i = blockIdx.x * 1024 + threadIdx.x;
    buf[threadIdx.x] = (i < n) ? cnt[i] : 0;
    __syncthreads();
    for (int off = 1; off < 1024; off <<= 1) {
        int t = ((int)threadIdx.x >= off) ? buf[threadIdx.x - off] : 0;
        __syncthreads();
        buf[threadIdx.x] += t;
        __syncthreads();
    }
    if (i < n) row_ptr[i + 1] = buf[threadIdx.x];
    if (threadIdx.x == 1023) btot[blockIdx.x] = buf[1023];
}

// (2) inclusive scan of block totals (nb <= 1024)
__global__ __launch_bounds__(1024) void scan_tops_kernel(int* __restrict__ btot, int nb) {
    __shared__ int buf[1024];
    buf[threadIdx.x] = ((int)threadIdx.x < nb) ? btot[threadIdx.x] : 0;
    __syncthreads();
    for (int off = 1; off < 1024; off <<= 1) {
        int t = ((int)threadIdx.x >= off) ? buf[threadIdx.x - off] : 0;
        __syncthreads();
        buf[threadIdx.x] += t;
        __syncthreads();
    }
    if ((int)threadIdx.x < nb) btot[threadIdx.x] = buf[threadIdx.x];
}

// (3) add block offsets; emit cursor + dinv
__global__ void scan_finalize_kernel(int* __restrict__ row_ptr, const int* __restrict__ btot,
        const int* __restrict__ cnt, int* __restrict__ cursor, float* __restrict__ dinv, int n) {
    int i = blockIdx.x * blockDim.x + threadIdx.x;
    if (i >= n) return;
    int blk = i >> 10;
    int off = blk ? btot[blk - 1] : 0;
    int incl = row_ptr[i + 1] + off;
    row_ptr[i + 1] = incl;
    cursor[i] = incl - cnt[i];
    dinv[i] = rsqrtf((float)(cnt[i] + 1));   // +1 self loop
    if (i == 0) row_ptr[0] = 0;
}

// scatter: single 8B store of {src, dinv[src]} per edge
__global__ void scatter_kernel(const int* __restrict__ es, const int* __restrict__ ed,
                               const float* __restrict__ dinv, int* __restrict__ cursor,
                               int2* __restrict__ csr_sn, int E) {
    int e = blockIdx.x * blockDim.x + threadIdx.x;
    if (e < E) {
        int s = es[e];
        int d = ed[e];
        int p = atomicAdd(&cursor[d], 1);
        csr_sn[p] = make_int2(s, __float_as_int(dinv[s]));
    }
}

// ---- W1 split + MFMA-native tiling ------------------------------------------
__global__ void wsplit_kernel(const float* __restrict__ W,
                              unsigned short* __restrict__ Th,
                              unsigned short* __restrict__ Tl, int K, int N, int nk) {
    int idx = blockIdx.x * 256 + threadIdx.x;
    if (idx >= K * N) return;
    int k = idx / N, n = idx % N;
    float f = W[idx];
    unsigned short h = f32_to_bf16(f);
    unsigned short l = f32_to_bf16(f - bf16_to_f32(h));
    int p = n >> 7, np = n & 127, t = k >> 5, kg = (k & 31) >> 3, ke = k & 7;
    size_t o = ((size_t)((p * nk + t) * 4 + kg) << 10) + np * 8 + ke;
    Th[o] = h;
    Tl[o] = l;
}

// ---- W2 split+transpose: W2[K][NC] f32 -> W2t_hi/lo[64][K] f16 (zero-padded)
__global__ void wsplit2_kernel(const float* __restrict__ W2,
                               f16* __restrict__ W2t_hi, f16* __restrict__ W2t_lo,
                               int K, int NC) {
    int idx = blockIdx.x * 256 + threadIdx.x;
    if (idx >= 64 * K) return;
    int n = idx / K, k = idx % K;
    float v = (n < NC) ? W2[(size_t)k * NC + n] : 0.f;
    f16 h = (f16)v;
    W2t_hi[idx] = h;
    W2t_lo[idx] = (f16)(v - (float)h);
}

// ---- GEMM1: h0[M,N](f16) = X[M,K](f32) @ W1[K,N] via MFMA bf16x3 ------------
#define G1_BM 128
#define G1_BN 128
#define G1_BK 32

__global__ __launch_bounds__(256) void gemm1_mfma(
        const float* __restrict__ X, const unsigned short* __restrict__ WtH,
        const unsigned short* __restrict__ WtL, f16* __restrict__ C,
        int M, int K, int N) {
    __shared__ __align__(16) unsigned char lds[32768];
    // [0,16384): A f32 swizzled; [16384,24576): Bh; [24576,32768): Bl

    const int tid  = threadIdx.x;
    const int lane = tid & 63;
    const int wave = tid >> 6;
    const int wm   = wave & 1;
    const int wn   = wave >> 1;
    const int m0   = blockIdx.x * G1_BM;
    const int pn   = blockIdx.y;          // 128-col panel index
    const int nk   = K / G1_BK;

    const float* Xbase[4];
    #pragma unroll
    for (int i = 0; i < 4; ++i) {
        int c   = i * 256 + tid;
        int row = c >> 3;
        int sl  = (c & 7) ^ (row & 7);    // pre-swizzled source slot
        int gr  = m0 + row;
        if (gr > M - 1) gr = M - 1;
        Xbase[i] = X + (size_t)gr * K + sl * 4;
    }
    const unsigned short* BhBase = WtH + ((size_t)pn * nk << 12) + (size_t)tid * 8;
    const unsigned short* BlBase = WtL + ((size_t)pn * nk << 12) + (size_t)tid * 8;

    f32x4 acc[4][4] = {};
    const int kq   = lane >> 4;
    const int frow = lane & 15;
    const int bOff = 16384 + (kq << 11) + ((wn * 64 + frow) << 4);

    for (int t = 0; t < nk; ++t) {
        const int k0 = t * G1_BK;
        #pragma unroll
        for (int i = 0; i < 4; ++i)
            glds16(Xbase[i] + k0, lds + i * 4096 + wave * 1024);
        const unsigned short* bh = BhBase + (size_t)t * 4096;
        const unsigned short* bl = BlBase + (size_t)t * 4096;
        glds16(bh,        lds + 16384 + wave * 1024);
        glds16(bh + 2048, lds + 20480 + wave * 1024);
        glds16(bl,        lds + 24576 + wave * 1024);
        glds16(bl + 2048, lds + 28672 + wave * 1024);
        __syncthreads();

        bf16x8 bhf[4], blf[4];
        #pragma unroll
        for (int nn = 0; nn < 4; ++nn) {
            bhf[nn] = *(const bf16x8*)(lds + bOff + nn * 256);
            blf[nn] = *(const bf16x8*)(lds + bOff + 8192 + nn * 256);
        }
        #pragma unroll
        for (int mm = 0; mm < 4; ++mm) {
            int ra = wm * 64 + mm * 16 + frow;
            int rb = ra << 7;
            int sw = (ra & 7) << 4;
            int s0 = kq << 1;
            f32x4 p0 = *(const f32x4*)(lds + rb + ((s0 << 4) ^ sw));
            f32x4 p1 = *(const f32x4*)(lds + rb + (((s0 + 1) << 4) ^ sw));
            float f[8] = {p0[0], p0[1], p0[2], p0[3], p1[0], p1[1], p1[2], p1[3]};
            u32x4 hv, lv;
            #pragma unroll
            for (int p = 0; p < 4; ++p) {
                unsigned b0 = __float_as_uint(f[2 * p]);
                unsigned b1 = __float_as_uint(f[2 * p + 1]);
                hv[p] = __builtin_amdgcn_perm(b1, b0, 0x07060302u);
                float l0 = f[2 * p]     - __uint_as_float(b0 & 0xFFFF0000u);
                float l1 = f[2 * p + 1] - __uint_as_float(b1 & 0xFFFF0000u);
                lv[p] = __builtin_amdgcn_perm(__float_as_uint(l1),
                                              __float_as_uint(l0), 0x07060302u);
            }
            union { u32x4 u; bf16x8 b; } ah, al;
            ah.u = hv; al.u = lv;
            #pragma unroll
            for (int nn = 0; nn < 4; ++nn)
                acc[mm][nn] = __builtin_amdgcn_mfma_f32_16x16x32_bf16(ah.b, bhf[nn], acc[mm][nn], 0, 0, 0);
            #pragma unroll
            for (int nn = 0; nn < 4; ++nn)
                acc[mm][nn] = __builtin_amdgcn_mfma_f32_16x16x32_bf16(ah.b, blf[nn], acc[mm][nn], 0, 0, 0);
            #pragma unroll
            for (int nn = 0; nn < 4; ++nn)
                acc[mm][nn] = __builtin_amdgcn_mfma_f32_16x16x32_bf16(al.b, bhf[nn], acc[mm][nn], 0, 0, 0);
        }
        __syncthreads();
    }

    const int n0 = pn * G1_BN;
    #pragma unroll
    for (int mm = 0; mm < 4; ++mm) {
        #pragma unroll
        for (int i = 0; i < 4; ++i) {
            int gr = m0 + wm * 64 + mm * 16 + kq * 4 + i;
            if (gr >= M) continue;
            #pragma unroll
            for (int nn = 0; nn < 4; ++nn) {
                int gc = n0 + wn * 64 + nn * 16 + frow;
                C[(size_t)gr * N + gc] = (f16)acc[mm][nn][i];
            }
        }
    }
}

// ---- fused agg1 + gemm2: 32 nodes/block, 4 waves, 8 nodes/wave (r12 best) ---
__global__ __launch_bounds__(256) void agg1_gemm2_kernel(
        const f16* __restrict__ h0, const float* __restrict__ dinv,
        const int* __restrict__ row_ptr, const int2* __restrict__ csr_sn,
        const float* __restrict__ b1,
        const f16* __restrict__ W2t_hi, const f16* __restrict__ W2t_lo,
        f16* __restrict__ g, int n, int K, int KC) {
    __shared__ __align__(16) f16 hs[32][264];

    const int tid  = threadIdx.x;
    const int lane = tid & 63;
    const int wave = tid >> 6;
    const int base = blockIdx.x * 32;
    const int c    = lane & 31;       // col group: cols c*8..c*8+7
    const int hf   = lane >> 5;       // half: which edge of the pair

    const f16x8* h0v8 = (const f16x8*)h0;    // row = 32 f16x8

    // bias for this lane's 8 cols
    float4 bA = ((const float4*)b1)[c * 2];
    float4 bB = ((const float4*)b1)[c * 2 + 1];
    float bb[8] = {bA.x, bA.y, bA.z, bA.w, bB.x, bB.y, bB.z, bB.w};

    // ---- phase 1: aggregate 8 nodes per wave into LDS -----------------------
    for (int i = 0; i < 8; ++i) {
        int wid = base + wave * 8 + i;
        float acc[8] = {};
        if (wid < n) {
            float di = dinv[wid];
            f16x8 vs = h0v8[(size_t)wid * 32 + c];
            float selfm = (hf == 0) ? di * di : 0.f;
            #pragma unroll
            for (int q = 0; q < 8; ++q) acc[q] = selfm * (float)vs[q];
            int beg = row_ptr[wid], end = row_ptr[wid + 1];
            int j = beg;
            for (; j + 4 <= end; j += 4) {              // 2 pairs in flight
                int2 eA = csr_sn[j + hf];
                int2 eB = csr_sn[j + 2 + hf];
                float nA = __int_as_float(eA.y) * di;
                float nB = __int_as_float(eB.y) * di;
                f16x8 uA = h0v8[(size_t)eA.x * 32 + c];
                f16x8 uB = h0v8[(size_t)eB.x * 32 + c];
                #pragma unroll
                for (int q = 0; q < 8; ++q) acc[q] = fmaf(nA, (float)uA[q], acc[q]);
                #pragma unroll
                for (int q = 0; q < 8; ++q) acc[q] = fmaf(nB, (float)uB[q], acc[q]);
            }
            for (; j < end; j += 2) {                   // 0..3 remainder, paired
                int  jj = j + hf;
                bool vld = jj < end;
                int2 eA = csr_sn[vld ? jj : j];
                float nA = vld ? __int_as_float(eA.y) * di : 0.f;
                f16x8 uA = h0v8[(size_t)eA.x * 32 + c];
                #pragma unroll
                for (int q = 0; q < 8; ++q) acc[q] = fmaf(nA, (float)uA[q], acc[q]);
            }
        }
        // cross-half reduce: both halves accumulated disjoint edges
        #pragma unroll
        for (int q = 0; q < 8; ++q) acc[q] += __shfl_xor(acc[q], 32);
        if (hf == 0) {
            f16x8 o;
            #pragma unroll
            for (int q = 0; q < 8; ++q)
                o[q] = (wid < n) ? (f16)fmaxf(acc[q] + bb[q], 0.f) : (f16)0.f;
            *(f16x8*)&hs[wave * 8 + i][c * 8] = o;
        }
    }
    __syncthreads();

    // ---- phase 2: g[32 x 64] = hs[32 x K] @ W2t^T (hi+lo), MFMA f16 ---------
    const int wm   = wave & 1;       // 16-row strip
    const int wn   = wave >> 1;      // 32-col strip
    const int kq   = lane >> 4;
    const int frow = lane & 15;
    const int koff = kq * 8;

    f32x4 acc2[2] = {};
    const f16* bh_base[2];
    const f16* bl_base[2];
    #pragma unroll
    for (int nn = 0; nn < 2; ++nn) {
        int r = wn * 32 + nn * 16 + frow;
        bh_base[nn] = W2t_hi + (size_t)r * K + koff;
        bl_base[nn] = W2t_lo + (size_t)r * K + koff;
    }

    for (int t = 0; t < K / 32; ++t) {
        const int kk = t * 32;
        f16x8 a = *(const f16x8*)&hs[wm * 16 + frow][kk + koff];
        #pragma unroll
        for (int nn = 0; nn < 2; ++nn) {
            f16x8 bh = *(const f16x8*)(bh_base[nn] + kk);
            f16x8 bl = *(const f16x8*)(bl_base[nn] + kk);
            acc2[nn] = __builtin_amdgcn_mfma_f32_16x16x32_f16(a, bh, acc2[nn], 0, 0, 0);
            acc2[nn] = __builtin_amdgcn_mfma_f32_16x16x32_f16(a, bl, acc2[nn], 0, 0, 0);
        }
    }

    // g padded to stride 64; cols 50..63 are zero automatically (W2t zero rows)
    #pragma unroll
    for (int i = 0; i < 4; ++i) {
        int gr = base + wm * 16 + kq * 4 + i;
        if (gr >= n) continue;
        #pragma unroll
        for (int nn = 0; nn < 2; ++nn) {
            int gc = wn * 32 + nn * 16 + frow;
            g[(size_t)gr * 64 + gc] = (f16)acc2[nn][i];
        }
    }
}

// ---- layer-2 aggregation + softmax: 8-deep unroll, int2 csr, stride-64 g ----
__global__ __launch_bounds__(256) void agg2_softmax_kernel(const f16* __restrict__ g,
        const float* __restrict__ dinv, const int* __restrict__ row_ptr,
        const int2* __restrict__ csr_sn, const float* __restrict__ b2,
        float* __restrict__ S, f16* __restrict__ Sh, int n, int KC) {
    int wid = (int)((blockIdx.x * (size_t)blockDim.x + threadIdx.x) >> 6);
    int lane = threadIdx.x & 63;
    if (wid >= n) return;
    bool act = lane < KC;
    float di = dinv[wid];
    float a0 = 0.f, a1 = 0.f, a2 = 0.f, a3 = 0.f;
    float a4 = 0.f, a5 = 0.f, a6 = 0.f, a7 = 0.f;
    a0 = di * di * (float)g[(size_t)wid * 64 + lane];   // pad cols are zero
    int beg = row_ptr[wid], end = row_ptr[wid + 1];
    int j = beg;
    for (; j + 8 <= end; j += 8) {
        int2 e0 = csr_sn[j],     e1 = csr_sn[j + 1];
        int2 e2 = csr_sn[j + 2], e3 = csr_sn[j + 3];
        int2 e4 = csr_sn[j + 4], e5 = csr_sn[j + 5];
        int2 e6 = csr_sn[j + 6], e7 = csr_sn[j + 7];
        float g0 = (float)g[(size_t)e0.x * 64 + lane];
        float g1 = (float)g[(size_t)e1.x * 64 + lane];
        float g2 = (float)g[(size_t)e2.x * 64 + lane];
        float g3 = (float)g[(size_t)e3.x * 64 + lane];
        float g4 = (float)g[(size_t)e4.x * 64 + lane];
        float g5 = (float)g[(size_t)e5.x * 64 + lane];
        float g6 = (float)g[(size_t)e6.x * 64 + lane];
        float g7 = (float)g[(size_t)e7.x * 64 + lane];
        a0 = fmaf(__int_as_float(e0.y) * di, g0, a0);
        a1 = fmaf(__int_as_float(e1.y) * di, g1, a1);
        a2 = fmaf(__int_as_float(e2.y) * di, g2, a2);
        a3 = fmaf(__int_as_float(e3.y) * di, g3, a3);
        a4 = fmaf(__int_as_float(e4.y) * di, g4, a4);
        a5 = fmaf(__int_as_float(e5.y) * di, g5, a5);
        a6 = fmaf(__int_as_float(e6.y) * di, g6, a6);
        a7 = fmaf(__int_as_float(e7.y) * di, g7, a7);
    }
    for (; j + 4 <= end; j += 4) {
        int2 e0 = csr_sn[j],     e1 = csr_sn[j + 1];
        int2 e2 = csr_sn[j + 2], e3 = csr_sn[j + 3];
        float g0 = (float)g[(size_t)e0.x * 64 + lane];
        float g1 = (float)g[(size_t)e1.x * 64 + lane];
        float g2 = (float)g[(size_t)e2.x * 64 + lane];
        float g3 = (float)g[(size_t)e3.x * 64 + lane];
        a0 = fmaf(__int_as_float(e0.y) * di, g0, a0);
        a1 = fmaf(__int_as_float(e1.y) * di, g1, a1);
        a2 = fmaf(__int_as_float(e2.y) * di, g2, a2);
        a3 = fmaf(__int_as_float(e3.y) * di, g3, a3);
    }
    for (; j < end; ++j) {
        int2 e0 = csr_sn[j];
        a0 = fmaf(__int_as_float(e0.y) * di, (float)g[(size_t)e0.x * 64 + lane], a0);
    }
    float acc = ((a0 + a1) + (a2 + a3)) + ((a4 + a5) + (a6 + a7));
    float val = act ? (acc + b2[lane]) : -INFINITY;
    float m = val;
    #pragma unroll
    for (int o = 32; o > 0; o >>= 1) m = fmaxf(m, __shfl_xor(m, o));
    float e = act ? expf(val - m) : 0.f;
    float ssum = e;
    #pragma unroll
    for (int o = 32; o > 0; o >>= 1) ssum += __shfl_xor(ssum, o);
    {
        float sv = act ? (e / ssum) : 0.f;
        if (act) S[(size_t)wid * KC + lane] = sv;
        Sh[(size_t)wid * 64 + lane] = (f16)sv;   // padded row (zeros 50..63)
    }
}

// ---- spatial loss: thread = 2 edges, packed-f16 dot -------------------------
__global__ __launch_bounds__(256) void loss_partial_kernel(const int* __restrict__ es,
        const int* __restrict__ ed, const float* __restrict__ pos,
        const f16* __restrict__ Sh, float* __restrict__ parts, int E) {
    float local = 0.f;
    int idx = blockIdx.x * blockDim.x + threadIdx.x;
    int stride = gridDim.x * blockDim.x;
    const int np = E >> 1;                       // E even (pairs)
    for (int p = idx; p < np; p += stride) {
        int2 s2 = ((const int2*)es)[p];
        int2 d2i = ((const int2*)ed)[p];
        #pragma unroll
        for (int u = 0; u < 2; ++u) {
            int s = u ? s2.y : s2.x;
            int d = u ? d2i.y : d2i.x;
            const f16x8* Sa = (const f16x8*)(Sh + (size_t)s * 64);
            const f16x8* Sb = (const f16x8*)(Sh + (size_t)d * 64);
            f16x8 dacc = {0, 0, 0, 0, 0, 0, 0, 0};
            #pragma unroll
            for (int q = 0; q < 7; ++q)
                dacc += Sa[q] * Sb[q];           // v_pk_fma_f16
            float dot = 0.f;
            #pragma unroll
            for (int k = 0; k < 8; ++k) dot += (float)dacc[k];
            float2 ps = ((const float2*)pos)[s];
            float2 pd = ((const float2*)pos)[d];
            float dx = ps.x - pd.x, dy = ps.y - pd.y;
            local = fmaf(dx * dx + dy * dy, dot, local);
        }
    }
    // tail (E odd) — handled by thread 0 only
    if ((E & 1) && idx == 0) {
        int e = E - 1;
        int s = es[e], d = ed[e];
        const f16x8* Sa = (const f16x8*)(Sh + (size_t)s * 64);
        const f16x8* Sb = (const f16x8*)(Sh + (size_t)d * 64);
        f16x8 dacc = {0, 0, 0, 0, 0, 0, 0, 0};
        #pragma unroll
        for (int q = 0; q < 7; ++q) dacc += Sa[q] * Sb[q];
        float dot = 0.f;
        #pragma unroll
        for (int k = 0; k < 8; ++k) dot += (float)dacc[k];
        float2 ps = ((const float2*)pos)[s];
        float2 pd = ((const float2*)pos)[d];
        float dx = ps.x - pd.x, dy = ps.y - pd.y;
        local = fmaf(dx * dx + dy * dy, dot, local);
    }
    __shared__ float red[256];
    red[threadIdx.x] = local;
    __syncthreads();
    for (int s = 128; s > 0; s >>= 1) {
        if ((int)threadIdx.x < s) red[threadIdx.x] += red[threadIdx.x + s];
        __syncthreads();
    }
    if (threadIdx.x == 0) parts[blockIdx.x] = red[0];
}

__global__ __launch_bounds__(1024) void loss_final_kernel(const float* __restrict__ parts,
        const float* __restrict__ sw, float* __restrict__ out, float invE) {
    __shared__ float red[1024];
    red[threadIdx.x] = parts[threadIdx.x];
    __syncthreads();
    for (int s = 512; s > 0; s >>= 1) {
        if ((int)threadIdx.x < s) red[threadIdx.x] += red[threadIdx.x + s];
        __syncthreads();
    }
    if (threadIdx.x == 0) out[0] = sw[0] * red[0] * invE;
}

// ---------------------------------------------------------------------------
extern "C" void kernel_launch(void* const* d_in, const int* in_sizes, int n_in,
                              void* d_out, int out_size, void* d_ws, size_t ws_size,
                              hipStream_t stream) {
    const float* x   = (const float*)d_in[0];
    const float* pos = (const float*)d_in[1];
    const float* W1  = (const float*)d_in[2];
    const float* b1  = (const float*)d_in[3];
    const float* W2  = (const float*)d_in[4];
    const float* b2  = (const float*)d_in[5];
    const float* sw  = (const float*)d_in[6];
    const void*  ei  = d_in[7];

    const int DH  = in_sizes[3];           // 256
    const int KC  = in_sizes[5];           // 50
    const int DIN = in_sizes[2] / DH;      // 512
    const int n   = in_sizes[0] / DIN;     // 50000
    const int E   = in_sizes[7] / 2;       // 800000

    char* p = (char*)d_ws;
    auto alloc = [&](size_t bytes) {
        char* r = p;
        p += (bytes + 255) & ~(size_t)255;
        return r;
    };
    int*   flag    = (int*)alloc(256);
    int*   es      = (int*)alloc((size_t)E * 4);
    int*   ed      = (int*)alloc((size_t)E * 4);
    int*   cnt     = (int*)alloc((size_t)n * 4);
    int*   cursor  = (int*)alloc((size_t)n * 4);
    int*   row_ptr = (int*)alloc(((size_t)n + 1) * 4);
    int*   btot    = (int*)alloc(1024 * 4);
    int2*  csr_sn  = (int2*)alloc((size_t)E * 8);
    float* dinv    = (float*)alloc((size_t)n * 4);
    float* parts   = (float*)alloc(1024 * 4);
    unsigned short* Wt_hi = (unsigned short*)alloc((size_t)DIN * DH * 2);
    unsigned short* Wt_lo = (unsigned short*)alloc((size_t)DIN * DH * 2);
    f16*   W2t_hi  = (f16*)alloc((size_t)64 * DH * 2);
    f16*   W2t_lo  = (f16*)alloc((size_t)64 * DH * 2);
    f16*   h0      = (f16*)alloc((size_t)n * DH * 2);
    f16*   g       = (f16*)alloc((size_t)n * 64 * 2);
    f16*   Sh      = (f16*)alloc((size_t)n * 64 * 2);

    float* S    = (float*)d_out;
    float* Lout = S + (size_t)n * KC;

    const int nb = (n + 1023) / 1024;
    const int nk = DIN / G1_BK;

    hipMemsetAsync(cnt, 0, (size_t)n * 4, stream);
    detect_i64_kernel<<<1, 256, 0, stream>>>((const unsigned*)ei, flag);
    convert_edges_kernel<<<(2 * E + 255) / 256, 256, 0, stream>>>(ei, es, ed, cnt, E, flag);
    scan_block_kernel<<<nb, 1024, 0, stream>>>(cnt, row_ptr, btot, n);
    scan_tops_kernel<<<1, 1024, 0, stream>>>(btot, nb);
    scan_finalize_kernel<<<(n + 255) / 256, 256, 0, stream>>>(row_ptr, btot, cnt, cursor, dinv, n);
    scatter_kernel<<<(E + 255) / 256, 256, 0, stream>>>(es, ed, dinv, cursor, csr_sn, E);

    // weight prep
    wsplit_kernel<<<(DIN * DH + 255) / 256, 256, 0, stream>>>(W1, Wt_hi, Wt_lo, DIN, DH, nk);
    wsplit2_kernel<<<(64 * DH + 255) / 256, 256, 0, stream>>>(W2, W2t_hi, W2t_lo, DH, KC);

    // h0 = x @ W1   (MFMA bf16x3; glds staging; fp16 output)
    dim3 g1((n + G1_BM - 1) / G1_BM, DH / G1_BN);
    gemm1_mfma<<<g1, 256, 0, stream>>>(x, Wt_hi, Wt_lo, h0, n, DIN, DH);

    // g = relu(Ahat @ h0 + b1) @ W2  (fused; 4 waves, 8 nodes/wave)
    agg1_gemm2_kernel<<<(n + 31) / 32, 256, 0, stream>>>(
        h0, dinv, row_ptr, csr_sn, b1, W2t_hi, W2t_lo, g, n, DH, KC);

    // s = Ahat @ g + b2 ; S = softmax(s)  (+ padded fp16 shadow for loss)
    agg2_softmax_kernel<<<(int)(((size_t)n * 64 + 255) / 256), 256, 0, stream>>>(
        g, dinv, row_ptr, csr_sn, b2, S, Sh, n, KC);

    // L = sw * sum(d2 * <S_s, S_d>) / E
    loss_partial_kernel<<<1024, 256, 0, stream>>>(es, ed, pos, Sh, parts, E);
    loss_final_kernel<<<1, 1024, 0, stream>>>(parts, sw, Lout, 1.0f / (float)E);
}

// Round 15
// 325.707 us; speedup vs baseline: 1.0279x; 1.0279x over previous
//
#include <hip/hip_runtime.h>
#include <math.h>

// ---------------------------------------------------------------------------
// DifferentiablePooling: 2-layer GCN + softmax + spatial loss
// Round 15: best-known recombination — r12 agg2 (4-deep, compact g) +
//           int2 csr_sn + packed-f16 loss dot (thread-per-edge).
// ---------------------------------------------------------------------------

typedef __attribute__((ext_vector_type(8))) short bf16x8;
typedef __attribute__((ext_vector_type(4))) float f32x4;
typedef __attribute__((ext_vector_type(4))) unsigned int u32x4;
typedef _Float16 f16;
typedef __attribute__((ext_vector_type(2))) _Float16 f16x2;
typedef __attribute__((ext_vector_type(4))) _Float16 f16x4;
typedef __attribute__((ext_vector_type(8))) _Float16 f16x8;

__device__ inline unsigned short f32_to_bf16(float f) {
    unsigned u = __float_as_uint(f);
    unsigned r = u + 0x7FFFu + ((u >> 16) & 1u);   // RTNE; inputs are finite
    return (unsigned short)(r >> 16);
}
__device__ inline float bf16_to_f32(unsigned short h) {
    return __uint_as_float((unsigned)h << 16);
}

// async global->LDS, 16B per lane; lptr must be wave-uniform (HW adds lane*16)
__device__ inline void glds16(const void* g, void* l) {
    __builtin_amdgcn_global_load_lds(
        (const __attribute__((address_space(1))) unsigned int*)g,
        (__attribute__((address_space(3))) unsigned int*)l, 16, 0, 0);
}

// ---- edge dtype detection (int64 vs int32 on device) ----------------------
__global__ void detect_i64_kernel(const unsigned* __restrict__ w, int* __restrict__ flag) {
    __shared__ int red[256];
    int cnt = 0;
    for (int i = threadIdx.x; i < 4096; i += 256)
        cnt += (w[2 * i + 1] == 0u) ? 1 : 0;   // high words of int64 are 0
    red[threadIdx.x] = cnt;
    __syncthreads();
    for (int s = 128; s > 0; s >>= 1) {
        if ((int)threadIdx.x < s) red[threadIdx.x] += red[threadIdx.x + s];
        __syncthreads();
    }
    if (threadIdx.x == 0) *flag = (red[0] > 2048) ? 1 : 0;
}

// convert + fused degree count (atomicAdd on dst)
__global__ void convert_edges_kernel(const void* __restrict__ ei, int* __restrict__ es,
                                     int* __restrict__ ed, int* __restrict__ cnt,
                                     int E, const int* __restrict__ flag) {
    int idx = blockIdx.x * blockDim.x + threadIdx.x;
    if (idx >= 2 * E) return;
    int v;
    if (*flag) v = (int)((const long long*)ei)[idx];
    else       v = ((const int*)ei)[idx];
    if (idx < E) es[idx] = v;
    else { ed[idx - E] = v; atomicAdd(&cnt[v], 1); }
}

// hierarchical scan: (1) per-block inclusive scan -> row_ptr[i+1], block totals
__global__ __launch_bounds__(1024) void scan_block_kernel(const int* __restrict__ cnt,
        int* __restrict__ row_ptr, int* __restrict__ btot, int n) {
    __shared__ int buf[1024];
    int i = blockIdx.x * 1024 + threadIdx.x;
    buf[threadIdx.x] = (i < n) ? cnt[i] : 0;
    __syncthreads();
    for (int off = 1; off < 1024; off <<= 1) {
        int t = ((int)threadIdx.x >= off) ? buf[threadIdx.x - off] : 0;
        __syncthreads();
        buf[threadIdx.x] += t;
        __syncthreads();
    }
    if (i < n) row_ptr[i + 1] = buf[threadIdx.x];
    if (threadIdx.x == 1023) btot[blockIdx.x] = buf[1023];
}

// (2) inclusive scan of block totals (nb <= 1024)
__global__ __launch_bounds__(1024) void scan_tops_kernel(int* __restrict__ btot, int nb) {
    __shared__ int buf[1024];
    buf[threadIdx.x] = ((int)threadIdx.x < nb) ? btot[threadIdx.x] : 0;
    __syncthreads();
    for (int off = 1; off < 1024; off <<= 1) {
        int t = ((int)threadIdx.x >= off) ? buf[threadIdx.x - off] : 0;
        __syncthreads();
        buf[threadIdx.x] += t;
        __syncthreads();
    }
    if ((int)threadIdx.x < nb) btot[threadIdx.x] = buf[threadIdx.x];
}

// (3) add block offsets; emit cursor + dinv
__global__ void scan_finalize_kernel(int* __restrict__ row_ptr, const int* __restrict__ btot,
        const int* __restrict__ cnt, int* __restrict__ cursor, float* __restrict__ dinv, int n) {
    int i = blockIdx.x * blockDim.x + threadIdx.x;
    if (i >= n) return;
    int blk = i >> 10;
    int off = blk ? btot[blk - 1] : 0;
    int incl = row_ptr[i + 1] + off;
    row_ptr[i + 1] = incl;
    cursor[i] = incl - cnt[i];
    dinv[i] = rsqrtf((float)(cnt[i] + 1));   // +1 self loop
    if (i == 0) row_ptr[0] = 0;
}

// scatter: single 8B store of {src, dinv[src]} per edge
__global__ void scatter_kernel(const int* __restrict__ es, const int* __restrict__ ed,
                               const float* __restrict__ dinv, int* __restrict__ cursor,
                               int2* __restrict__ csr_sn, int E) {
    int e = blockIdx.x * blockDim.x + threadIdx.x;
    if (e < E) {
        int s = es[e];
        int d = ed[e];
        int p = atomicAdd(&cursor[d], 1);
        csr_sn[p] = make_int2(s, __float_as_int(dinv[s]));
    }
}

// ---- W1 split + MFMA-native tiling ------------------------------------------
__global__ void wsplit_kernel(const float* __restrict__ W,
                              unsigned short* __restrict__ Th,
                              unsigned short* __restrict__ Tl, int K, int N, int nk) {
    int idx = blockIdx.x * 256 + threadIdx.x;
    if (idx >= K * N) return;
    int k = idx / N, n = idx % N;
    float f = W[idx];
    unsigned short h = f32_to_bf16(f);
    unsigned short l = f32_to_bf16(f - bf16_to_f32(h));
    int p = n >> 7, np = n & 127, t = k >> 5, kg = (k & 31) >> 3, ke = k & 7;
    size_t o = ((size_t)((p * nk + t) * 4 + kg) << 10) + np * 8 + ke;
    Th[o] = h;
    Tl[o] = l;
}

// ---- W2 split+transpose: W2[K][NC] f32 -> W2t_hi/lo[64][K] f16 (zero-padded)
__global__ void wsplit2_kernel(const float* __restrict__ W2,
                               f16* __restrict__ W2t_hi, f16* __restrict__ W2t_lo,
                               int K, int NC) {
    int idx = blockIdx.x * 256 + threadIdx.x;
    if (idx >= 64 * K) return;
    int n = idx / K, k = idx % K;
    float v = (n < NC) ? W2[(size_t)k * NC + n] : 0.f;
    f16 h = (f16)v;
    W2t_hi[idx] = h;
    W2t_lo[idx] = (f16)(v - (float)h);
}

// ---- GEMM1: h0[M,N](f16) = X[M,K](f32) @ W1[K,N] via MFMA bf16x3 ------------
#define G1_BM 128
#define G1_BN 128
#define G1_BK 32

__global__ __launch_bounds__(256) void gemm1_mfma(
        const float* __restrict__ X, const unsigned short* __restrict__ WtH,
        const unsigned short* __restrict__ WtL, f16* __restrict__ C,
        int M, int K, int N) {
    __shared__ __align__(16) unsigned char lds[32768];
    // [0,16384): A f32 swizzled; [16384,24576): Bh; [24576,32768): Bl

    const int tid  = threadIdx.x;
    const int lane = tid & 63;
    const int wave = tid >> 6;
    const int wm   = wave & 1;
    const int wn   = wave >> 1;
    const int m0   = blockIdx.x * G1_BM;
    const int pn   = blockIdx.y;          // 128-col panel index
    const int nk   = K / G1_BK;

    const float* Xbase[4];
    #pragma unroll
    for (int i = 0; i < 4; ++i) {
        int c   = i * 256 + tid;
        int row = c >> 3;
        int sl  = (c & 7) ^ (row & 7);    // pre-swizzled source slot
        int gr  = m0 + row;
        if (gr > M - 1) gr = M - 1;
        Xbase[i] = X + (size_t)gr * K + sl * 4;
    }
    const unsigned short* BhBase = WtH + ((size_t)pn * nk << 12) + (size_t)tid * 8;
    const unsigned short* BlBase = WtL + ((size_t)pn * nk << 12) + (size_t)tid * 8;

    f32x4 acc[4][4] = {};
    const int kq   = lane >> 4;
    const int frow = lane & 15;
    const int bOff = 16384 + (kq << 11) + ((wn * 64 + frow) << 4);

    for (int t = 0; t < nk; ++t) {
        const int k0 = t * G1_BK;
        #pragma unroll
        for (int i = 0; i < 4; ++i)
            glds16(Xbase[i] + k0, lds + i * 4096 + wave * 1024);
        const unsigned short* bh = BhBase + (size_t)t * 4096;
        const unsigned short* bl = BlBase + (size_t)t * 4096;
        glds16(bh,        lds + 16384 + wave * 1024);
        glds16(bh + 2048, lds + 20480 + wave * 1024);
        glds16(bl,        lds + 24576 + wave * 1024);
        glds16(bl + 2048, lds + 28672 + wave * 1024);
        __syncthreads();

        bf16x8 bhf[4], blf[4];
        #pragma unroll
        for (int nn = 0; nn < 4; ++nn) {
            bhf[nn] = *(const bf16x8*)(lds + bOff + nn * 256);
            blf[nn] = *(const bf16x8*)(lds + bOff + 8192 + nn * 256);
        }
        #pragma unroll
        for (int mm = 0; mm < 4; ++mm) {
            int ra = wm * 64 + mm * 16 + frow;
            int rb = ra << 7;
            int sw = (ra & 7) << 4;
            int s0 = kq << 1;
            f32x4 p0 = *(const f32x4*)(lds + rb + ((s0 << 4) ^ sw));
            f32x4 p1 = *(const f32x4*)(lds + rb + (((s0 + 1) << 4) ^ sw));
            float f[8] = {p0[0], p0[1], p0[2], p0[3], p1[0], p1[1], p1[2], p1[3]};
            u32x4 hv, lv;
            #pragma unroll
            for (int p = 0; p < 4; ++p) {
                unsigned b0 = __float_as_uint(f[2 * p]);
                unsigned b1 = __float_as_uint(f[2 * p + 1]);
                hv[p] = __builtin_amdgcn_perm(b1, b0, 0x07060302u);
                float l0 = f[2 * p]     - __uint_as_float(b0 & 0xFFFF0000u);
                float l1 = f[2 * p + 1] - __uint_as_float(b1 & 0xFFFF0000u);
                lv[p] = __builtin_amdgcn_perm(__float_as_uint(l1),
                                              __float_as_uint(l0), 0x07060302u);
            }
            union { u32x4 u; bf16x8 b; } ah, al;
            ah.u = hv; al.u = lv;
            #pragma unroll
            for (int nn = 0; nn < 4; ++nn)
                acc[mm][nn] = __builtin_amdgcn_mfma_f32_16x16x32_bf16(ah.b, bhf[nn], acc[mm][nn], 0, 0, 0);
            #pragma unroll
            for (int nn = 0; nn < 4; ++nn)
                acc[mm][nn] = __builtin_amdgcn_mfma_f32_16x16x32_bf16(ah.b, blf[nn], acc[mm][nn], 0, 0, 0);
            #pragma unroll
            for (int nn = 0; nn < 4; ++nn)
                acc[mm][nn] = __builtin_amdgcn_mfma_f32_16x16x32_bf16(al.b, bhf[nn], acc[mm][nn], 0, 0, 0);
        }
        __syncthreads();
    }

    const int n0 = pn * G1_BN;
    #pragma unroll
    for (int mm = 0; mm < 4; ++mm) {
        #pragma unroll
        for (int i = 0; i < 4; ++i) {
            int gr = m0 + wm * 64 + mm * 16 + kq * 4 + i;
            if (gr >= M) continue;
            #pragma unroll
            for (int nn = 0; nn < 4; ++nn) {
                int gc = n0 + wn * 64 + nn * 16 + frow;
                C[(size_t)gr * N + gc] = (f16)acc[mm][nn][i];
            }
        }
    }
}

// ---- fused agg1 + gemm2: 32 nodes/block, 4 waves, 8 nodes/wave --------------
__global__ __launch_bounds__(256) void agg1_gemm2_kernel(
        const f16* __restrict__ h0, const float* __restrict__ dinv,
        const int* __restrict__ row_ptr, const int2* __restrict__ csr_sn,
        const float* __restrict__ b1,
        const f16* __restrict__ W2t_hi, const f16* __restrict__ W2t_lo,
        f16* __restrict__ g, int n, int K, int KC) {
    __shared__ __align__(16) f16 hs[32][264];

    const int tid  = threadIdx.x;
    const int lane = tid & 63;
    const int wave = tid >> 6;
    const int base = blockIdx.x * 32;
    const int c    = lane & 31;       // col group: cols c*8..c*8+7
    const int hf   = lane >> 5;       // half: which edge of the pair

    const f16x8* h0v8 = (const f16x8*)h0;    // row = 32 f16x8

    // bias for this lane's 8 cols
    float4 bA = ((const float4*)b1)[c * 2];
    float4 bB = ((const float4*)b1)[c * 2 + 1];
    float bb[8] = {bA.x, bA.y, bA.z, bA.w, bB.x, bB.y, bB.z, bB.w};

    // ---- phase 1: aggregate 8 nodes per wave into LDS -----------------------
    for (int i = 0; i < 8; ++i) {
        int wid = base + wave * 8 + i;
        float acc[8] = {};
        if (wid < n) {
            float di = dinv[wid];
            f16x8 vs = h0v8[(size_t)wid * 32 + c];
            float selfm = (hf == 0) ? di * di : 0.f;
            #pragma unroll
            for (int q = 0; q < 8; ++q) acc[q] = selfm * (float)vs[q];
            int beg = row_ptr[wid], end = row_ptr[wid + 1];
            int j = beg;
            for (; j + 4 <= end; j += 4) {              // 2 pairs in flight
                int2 eA = csr_sn[j + hf];
                int2 eB = csr_sn[j + 2 + hf];
                float nA = __int_as_float(eA.y) * di;
                float nB = __int_as_float(eB.y) * di;
                f16x8 uA = h0v8[(size_t)eA.x * 32 + c];
                f16x8 uB = h0v8[(size_t)eB.x * 32 + c];
                #pragma unroll
                for (int q = 0; q < 8; ++q) acc[q] = fmaf(nA, (float)uA[q], acc[q]);
                #pragma unroll
                for (int q = 0; q < 8; ++q) acc[q] = fmaf(nB, (float)uB[q], acc[q]);
            }
            for (; j < end; j += 2) {                   // 0..3 remainder, paired
                int  jj = j + hf;
                bool vld = jj < end;
                int2 eA = csr_sn[vld ? jj : j];
                float nA = vld ? __int_as_float(eA.y) * di : 0.f;
                f16x8 uA = h0v8[(size_t)eA.x * 32 + c];
                #pragma unroll
                for (int q = 0; q < 8; ++q) acc[q] = fmaf(nA, (float)uA[q], acc[q]);
            }
        }
        // cross-half reduce: both halves accumulated disjoint edges
        #pragma unroll
        for (int q = 0; q < 8; ++q) acc[q] += __shfl_xor(acc[q], 32);
        if (hf == 0) {
            f16x8 o;
            #pragma unroll
            for (int q = 0; q < 8; ++q)
                o[q] = (wid < n) ? (f16)fmaxf(acc[q] + bb[q], 0.f) : (f16)0.f;
            *(f16x8*)&hs[wave * 8 + i][c * 8] = o;
        }
    }
    __syncthreads();

    // ---- phase 2: g[32 x KC] = hs[32 x K] @ W2t^T (hi+lo), MFMA f16 ---------
    const int wm   = wave & 1;       // 16-row strip
    const int wn   = wave >> 1;      // 32-col strip
    const int kq   = lane >> 4;
    const int frow = lane & 15;
    const int koff = kq * 8;

    f32x4 acc2[2] = {};
    const f16* bh_base[2];
    const f16* bl_base[2];
    #pragma unroll
    for (int nn = 0; nn < 2; ++nn) {
        int r = wn * 32 + nn * 16 + frow;
        bh_base[nn] = W2t_hi + (size_t)r * K + koff;
        bl_base[nn] = W2t_lo + (size_t)r * K + koff;
    }

    for (int t = 0; t < K / 32; ++t) {
        const int kk = t * 32;
        f16x8 a = *(const f16x8*)&hs[wm * 16 + frow][kk + koff];
        #pragma unroll
        for (int nn = 0; nn < 2; ++nn) {
            f16x8 bh = *(const f16x8*)(bh_base[nn] + kk);
            f16x8 bl = *(const f16x8*)(bl_base[nn] + kk);
            acc2[nn] = __builtin_amdgcn_mfma_f32_16x16x32_f16(a, bh, acc2[nn], 0, 0, 0);
            acc2[nn] = __builtin_amdgcn_mfma_f32_16x16x32_f16(a, bl, acc2[nn], 0, 0, 0);
        }
    }

    #pragma unroll
    for (int i = 0; i < 4; ++i) {
        int gr = base + wm * 16 + kq * 4 + i;
        if (gr >= n) continue;
        #pragma unroll
        for (int nn = 0; nn < 2; ++nn) {
            int gc = wn * 32 + nn * 16 + frow;
            if (gc < KC) g[(size_t)gr * KC + gc] = (f16)acc2[nn][i];
        }
    }
}

// ---- layer-2 aggregation + softmax: 4-deep unroll, int2 csr, compact g ------
__global__ __launch_bounds__(256) void agg2_softmax_kernel(const f16* __restrict__ g,
        const float* __restrict__ dinv, const int* __restrict__ row_ptr,
        const int2* __restrict__ csr_sn, const float* __restrict__ b2,
        float* __restrict__ S, f16* __restrict__ Sh, int n, int KC) {
    int wid = (int)((blockIdx.x * (size_t)blockDim.x + threadIdx.x) >> 6);
    int lane = threadIdx.x & 63;
    if (wid >= n) return;
    bool act = lane < KC;
    size_t gidx = act ? (size_t)lane : 0;
    float di = dinv[wid];
    float a0 = 0.f, a1 = 0.f, a2 = 0.f, a3 = 0.f;
    if (act) a0 = di * di * (float)g[(size_t)wid * KC + lane];
    int beg = row_ptr[wid], end = row_ptr[wid + 1];
    int j = beg;
    for (; j + 4 <= end; j += 4) {
        int2 e0 = csr_sn[j],     e1 = csr_sn[j + 1];
        int2 e2 = csr_sn[j + 2], e3 = csr_sn[j + 3];
        float g0 = (float)g[(size_t)e0.x * KC + gidx];
        float g1 = (float)g[(size_t)e1.x * KC + gidx];
        float g2 = (float)g[(size_t)e2.x * KC + gidx];
        float g3 = (float)g[(size_t)e3.x * KC + gidx];
        a0 = fmaf(__int_as_float(e0.y) * di, g0, a0);
        a1 = fmaf(__int_as_float(e1.y) * di, g1, a1);
        a2 = fmaf(__int_as_float(e2.y) * di, g2, a2);
        a3 = fmaf(__int_as_float(e3.y) * di, g3, a3);
    }
    for (; j < end; ++j) {
        int2 e0 = csr_sn[j];
        a0 = fmaf(__int_as_float(e0.y) * di, (float)g[(size_t)e0.x * KC + gidx], a0);
    }
    float acc = (a0 + a1) + (a2 + a3);
    float val = act ? (acc + b2[lane]) : -INFINITY;
    float m = val;
    #pragma unroll
    for (int o = 32; o > 0; o >>= 1) m = fmaxf(m, __shfl_xor(m, o));
    float e = act ? expf(val - m) : 0.f;
    float ssum = e;
    #pragma unroll
    for (int o = 32; o > 0; o >>= 1) ssum += __shfl_xor(ssum, o);
    {
        float sv = act ? (e / ssum) : 0.f;
        if (act) S[(size_t)wid * KC + lane] = sv;
        Sh[(size_t)wid * 64 + lane] = (f16)sv;   // padded row (zeros 50..63)
    }
}

// ---- spatial loss: thread-per-edge grid-stride, packed-f16 dot --------------
__global__ __launch_bounds__(256) void loss_partial_kernel(const int* __restrict__ es,
        const int* __restrict__ ed, const float* __restrict__ pos,
        const f16* __restrict__ Sh, float* __restrict__ parts, int E) {
    float local = 0.f;
    int stride = gridDim.x * blockDim.x;
    for (int e = blockIdx.x * blockDim.x + threadIdx.x; e < E; e += stride) {
        int s = es[e], d = ed[e];
        float2 ps = ((const float2*)pos)[s];
        float2 pd = ((const float2*)pos)[d];
        float dx = ps.x - pd.x, dy = ps.y - pd.y;
        float d2 = dx * dx + dy * dy;
        const f16x8* Sa = (const f16x8*)(Sh + (size_t)s * 64);
        const f16x8* Sb = (const f16x8*)(Sh + (size_t)d * 64);
        f16x8 dacc = {0, 0, 0, 0, 0, 0, 0, 0};
        #pragma unroll
        for (int q = 0; q < 7; ++q)
            dacc += Sa[q] * Sb[q];               // v_pk_fma_f16
        float dot = 0.f;
        #pragma unroll
        for (int k = 0; k < 8; ++k) dot += (float)dacc[k];
        local = fmaf(d2, dot, local);
    }
    __shared__ float red[256];
    red[threadIdx.x] = local;
    __syncthreads();
    for (int s = 128; s > 0; s >>= 1) {
        if ((int)threadIdx.x < s) red[threadIdx.x] += red[threadIdx.x + s];
        __syncthreads();
    }
    if (threadIdx.x == 0) parts[blockIdx.x] = red[0];
}

__global__ __launch_bounds__(1024) void loss_final_kernel(const float* __restrict__ parts,
        const float* __restrict__ sw, float* __restrict__ out, float invE) {
    __shared__ float red[1024];
    red[threadIdx.x] = parts[threadIdx.x];
    __syncthreads();
    for (int s = 512; s > 0; s >>= 1) {
        if ((int)threadIdx.x < s) red[threadIdx.x] += red[threadIdx.x + s];
        __syncthreads();
    }
    if (threadIdx.x == 0) out[0] = sw[0] * red[0] * invE;
}

// ---------------------------------------------------------------------------
extern "C" void kernel_launch(void* const* d_in, const int* in_sizes, int n_in,
                              void* d_out, int out_size, void* d_ws, size_t ws_size,
                              hipStream_t stream) {
    const float* x   = (const float*)d_in[0];
    const float* pos = (const float*)d_in[1];
    const float* W1  = (const float*)d_in[2];
    const float* b1  = (const float*)d_in[3];
    const float* W2  = (const float*)d_in[4];
    const float* b2  = (const float*)d_in[5];
    const float* sw  = (const float*)d_in[6];
    const void*  ei  = d_in[7];

    const int DH  = in_sizes[3];           // 256
    const int KC  = in_sizes[5];           // 50
    const int DIN = in_sizes[2] / DH;      // 512
    const int n   = in_sizes[0] / DIN;     // 50000
    const int E   = in_sizes[7] / 2;       // 800000

    char* p = (char*)d_ws;
    auto alloc = [&](size_t bytes) {
        char* r = p;
        p += (bytes + 255) & ~(size_t)255;
        return r;
    };
    int*   flag    = (int*)alloc(256);
    int*   es      = (int*)alloc((size_t)E * 4);
    int*   ed      = (int*)alloc((size_t)E * 4);
    int*   cnt     = (int*)alloc((size_t)n * 4);
    int*   cursor  = (int*)alloc((size_t)n * 4);
    int*   row_ptr = (int*)alloc(((size_t)n + 1) * 4);
    int*   btot    = (int*)alloc(1024 * 4);
    int2*  csr_sn  = (int2*)alloc((size_t)E * 8);
    float* dinv    = (float*)alloc((size_t)n * 4);
    float* parts   = (float*)alloc(1024 * 4);
    unsigned short* Wt_hi = (unsigned short*)alloc((size_t)DIN * DH * 2);
    unsigned short* Wt_lo = (unsigned short*)alloc((size_t)DIN * DH * 2);
    f16*   W2t_hi  = (f16*)alloc((size_t)64 * DH * 2);
    f16*   W2t_lo  = (f16*)alloc((size_t)64 * DH * 2);
    f16*   h0      = (f16*)alloc((size_t)n * DH * 2);
    f16*   g       = (f16*)alloc((size_t)n * KC * 2);
    f16*   Sh      = (f16*)alloc((size_t)n * 64 * 2);

    float* S    = (float*)d_out;
    float* Lout = S + (size_t)n * KC;

    const int nb = (n + 1023) / 1024;
    const int nk = DIN / G1_BK;

    hipMemsetAsync(cnt, 0, (size_t)n * 4, stream);
    detect_i64_kernel<<<1, 256, 0, stream>>>((const unsigned*)ei, flag);
    convert_edges_kernel<<<(2 * E + 255) / 256, 256, 0, stream>>>(ei, es, ed, cnt, E, flag);
    scan_block_kernel<<<nb, 1024, 0, stream>>>(cnt, row_ptr, btot, n);
    scan_tops_kernel<<<1, 1024, 0, stream>>>(btot, nb);
    scan_finalize_kernel<<<(n + 255) / 256, 256, 0, stream>>>(row_ptr, btot, cnt, cursor, dinv, n);
    scatter_kernel<<<(E + 255) / 256, 256, 0, stream>>>(es, ed, dinv, cursor, csr_sn, E);

    // weight prep
    wsplit_kernel<<<(DIN * DH + 255) / 256, 256, 0, stream>>>(W1, Wt_hi, Wt_lo, DIN, DH, nk);
    wsplit2_kernel<<<(64 * DH + 255) / 256, 256, 0, stream>>>(W2, W2t_hi, W2t_lo, DH, KC);

    // h0 = x @ W1   (MFMA bf16x3; glds staging; fp16 output)
    dim3 g1((n + G1_BM - 1) / G1_BM, DH / G1_BN);
    gemm1_mfma<<<g1, 256, 0, stream>>>(x, Wt_hi, Wt_lo, h0, n, DIN, DH);

    // g = relu(Ahat @ h0 + b1) @ W2  (fused; 4 waves, 8 nodes/wave)
    agg1_gemm2_kernel<<<(n + 31) / 32, 256, 0, stream>>>(
        h0, dinv, row_ptr, csr_sn, b1, W2t_hi, W2t_lo, g, n, DH, KC);

    // s = Ahat @ g + b2 ; S = softmax(s)  (+ padded fp16 shadow for loss)
    agg2_softmax_kernel<<<(int)(((size_t)n * 64 + 255) / 256), 256, 0, stream>>>(
        g, dinv, row_ptr, csr_sn, b2, S, Sh, n, KC);

    // L = sw * sum(d2 * <S_s, S_d>) / E
    loss_partial_kernel<<<1024, 256, 0, stream>>>(es, ed, pos, Sh, parts, E);
    loss_final_kernel<<<1, 1024, 0, stream>>>(parts, sw, Lout, 1.0f / (float)E);
}